// Round 15
// baseline (1351.665 us; speedup 1.0000x reference)
//
#include <hip/hip_runtime.h>

namespace {

typedef __attribute__((ext_vector_type(8))) short short8;
typedef __attribute__((ext_vector_type(4))) float f32x4;

constexpr int kNP = 50000, kNT = 200000, kNA = 20000;
constexpr int kEPT = 1000000, kETP = 1000000, kEAT = 400000, kETA = 400000;
constexpr int DIN = 128, DH = 256, DO = 128;
constexpr int per1 = DIN * DH;  // 32768
constexpr int per2 = DH * DO;   // 32768

__device__ __forceinline__ float bf2f(short u) {
  union { unsigned int i; float f; } c;
  c.i = ((unsigned int)(unsigned short)u) << 16;
  return c.f;
}
__device__ __forceinline__ short f2bf(float f) {
  union { float f; unsigned int i; } c;
  c.f = f;
  unsigned int r = c.i + 0x7fffu + ((c.i >> 16) & 1u);  // RNE
  return (short)(r >> 16);
}

inline int cdiv(int a, int b) { return (a + b - 1) / b; }
constexpr int ccdiv(int a, int b) { return (a + b - 1) / b; }

// ---------------- fused convert: xpe, xae, xt -> bf16 ----------------

__global__ __launch_bounds__(256) void cvt_all(
    const float* __restrict__ x_p, const float* __restrict__ emb_p,
    short* __restrict__ xpeb, const float* __restrict__ x_a,
    const float* __restrict__ emb_a, short* __restrict__ xaeb,
    const float* __restrict__ x_t, short* __restrict__ xtb) {
  constexpr int N0 = kNP * DIN / 8;
  constexpr int N1 = N0 + kNA * DIN / 8;
  constexpr int N2 = N1 + kNT * DIN / 8;
  int g = blockIdx.x * 256 + threadIdx.x;
  const float* a;
  const float* b = nullptr;
  short* o;
  int i;
  if (g < N0) { a = x_p; b = emb_p; o = xpeb; i = g; }
  else if (g < N1) { a = x_a; b = emb_a; o = xaeb; i = g - N0; }
  else if (g < N2) { a = x_t; o = xtb; i = g - N1; }
  else return;
  const float4* a4 = reinterpret_cast<const float4*>(a);
  float4 x0 = a4[2 * i], x1 = a4[2 * i + 1];
  if (b != nullptr) {
    const float4* b4 = reinterpret_cast<const float4*>(b);
    float4 y0 = b4[2 * i], y1 = b4[2 * i + 1];
    x0.x += y0.x; x0.y += y0.y; x0.z += y0.z; x0.w += y0.w;
    x1.x += y1.x; x1.y += y1.y; x1.z += y1.z; x1.w += y1.w;
  }
  short8 w;
  w[0] = f2bf(x0.x); w[1] = f2bf(x0.y); w[2] = f2bf(x0.z); w[3] = f2bf(x0.w);
  w[4] = f2bf(x1.x); w[5] = f2bf(x1.y); w[6] = f2bf(x1.z); w[7] = f2bf(x1.w);
  reinterpret_cast<short8*>(o)[i] = w;
}

// ---------------- fused weight prep (row-major bf16 + fp32 biases) -----------

__global__ __launch_bounds__(256) void prep_all(
    const float* __restrict__ W1l, const float* __restrict__ W1r,
    const float* __restrict__ W2l, const float* __restrict__ Wres,
    const float* __restrict__ W2r, const float* __restrict__ bres,
    const float* __restrict__ b2, const float* __restrict__ b1,
    short* __restrict__ w1l_rm, short* __restrict__ w1r_rm,
    short* __restrict__ w1rc_rm, short* __restrict__ w2l_rm,
    short* __restrict__ wc_rm, float* __restrict__ bc,
    float* __restrict__ b1ct) {
  constexpr int P0 = 4 * per1;
  constexpr int P1 = P0 + 4 * per1;
  constexpr int P2 = P1 + per1;
  constexpr int P3 = P2 + 4 * per2;
  constexpr int P4 = P3 + 3 * per2;
  constexpr int P5 = P4 + DH;
  int g = blockIdx.x * 256 + threadIdx.x;
  if (g < P0) {
    int e = g / per1;
    float s = (e == 0 || e == 2) ? 0.5f : 1.0f;
    w1l_rm[g] = f2bf(W1l[g] * s);
  } else if (g < P1) {
    int l = g - P0;
    w1r_rm[l] = f2bf(W1r[l]);
  } else if (g < P2) {
    int l = g - P1;
    w1rc_rm[l] = f2bf(0.5f * (W1r[l] + W1r[2 * per1 + l]));
  } else if (g < P3) {
    int l = g - P2;
    int e = l / per2;
    float s = (e == 0 || e == 2) ? 0.5f : 1.0f;
    w2l_rm[l] = f2bf(W2l[l] * s);
  } else if (g < P4) {
    int l = g - P3;
    {
      int b = l / per2;
      int idx = l - b * per2;
      int resIdx = (b == 0) ? 1 : (b == 1) ? 0 : 2;
      float v = Wres[(size_t)resIdx * per2 + idx];
      if (b == 0)
        v += 0.5f * (W2r[idx] + W2r[(size_t)2 * per2 + idx]);
      else if (b == 1)
        v += W2r[(size_t)1 * per2 + idx];
      else
        v += W2r[(size_t)3 * per2 + idx];
      wc_rm[l] = f2bf(v);
    }
    if (l < 3 * DO) {
      int b = l / DO;
      int o = l - b * DO;
      int resIdx = (b == 0) ? 1 : (b == 1) ? 0 : 2;
      float v = bres[resIdx * DO + o];
      if (b == 0)
        v += 0.5f * (b2[0 * DO + o] + b2[2 * DO + o]);
      else if (b == 1)
        v += b2[1 * DO + o];
      else
        v += b2[3 * DO + o];
      bc[l] = v;
    }
  } else if (g < P5) {
    int l = g - P4;
    b1ct[l] = 0.5f * (b1[l] + b1[2 * DH + l]);
  }
}

// ---------------- fragment swizzle (all weights, one launch) ------------------
// bf16 [D][Kk] row-major -> [D/16][Kk/32][lane=ls*16+lr][8]

__device__ __forceinline__ void swz1(const short* __restrict__ in,
                                     short* __restrict__ out, int t, int D,
                                     int Kk) {
  int kch = Kk / 32;
  int per8 = D * Kk / 8;
  int m = t / per8;
  int tt = t - m * per8;
  int cg = tt / (kch * 64);
  int r1 = tt - cg * kch * 64;
  int kc = r1 >> 6;
  int lane = r1 & 63;
  int ls = lane >> 4, lr = lane & 15;
  const short* src = in + (size_t)m * D * Kk + (size_t)(cg * 16 + lr) * Kk +
                     kc * 32 + ls * 8;
  short8 v = *reinterpret_cast<const short8*>(src);
  reinterpret_cast<short8*>(out + (size_t)m * D * Kk)[tt] = v;
}

__global__ __launch_bounds__(256) void swizzle_all(
    const short* __restrict__ w1l_rm, short* __restrict__ w1lb,
    const short* __restrict__ w1r_rm, short* __restrict__ w1rb,
    const short* __restrict__ w1rc_rm, short* __restrict__ w1rcb,
    const short* __restrict__ w2l_rm, short* __restrict__ w2lb,
    const short* __restrict__ wc_rm, short* __restrict__ wcb,
    short* __restrict__ wdual) {
  constexpr int S0 = 4 * per1 / 8;         // 16384
  constexpr int S1 = S0 + 4 * per1 / 8;    // 32768
  constexpr int S2 = S1 + per1 / 8;        // 36864
  constexpr int S3 = S2 + 4 * per2 / 8;    // 53248
  constexpr int S4 = S3 + 3 * per2 / 8;    // 65536
  constexpr int S5 = S4 + per2 / 8;        // 69632
  constexpr int S6 = S5 + per2 / 8;        // 73728
  constexpr int S7 = S6 + per2 / 8;        // 77824
  int g = blockIdx.x * 256 + threadIdx.x;
  if (g < S0) swz1(w1l_rm, w1lb, g, DH, DIN);
  else if (g < S1) swz1(w1r_rm, w1rb, g - S0, DH, DIN);
  else if (g < S2) swz1(w1rc_rm, w1rcb, g - S1, DH, DIN);
  else if (g < S3) swz1(w2l_rm, w2lb, g - S2, DO, DH);
  else if (g < S4) swz1(wc_rm, wcb, g - S3, DO, DH);
  else if (g < S5) swz1(wc_rm, wdual, g - S4, DO, DH);                 // Wc0
  else if (g < S6) swz1(w2l_rm + per2, wdual + per2, g - S5, DO, DH);  // W2l1
  else if (g < S7) swz1(w2l_rm + 3 * per2, wdual + 2 * per2, g - S6, DO, DH);
}

// ---------------- CSR build v2: bucketed counting sort ----------------

constexpr int NB0 = ccdiv(kNT, 256);
constexpr int NB1 = ccdiv(kNP, 256);
constexpr int NB2 = ccdiv(kNT, 256);
constexpr int NB3 = ccdiv(kNA, 256);
constexpr int NBTOT = NB0 + NB1 + NB2 + NB3;
constexpr int BBTOT = NBTOT + 4;
constexpr int CHUNK = 16384;
constexpr int C0 = ccdiv(kEPT, CHUNK), C1 = ccdiv(kETP, CHUNK),
              C2 = ccdiv(kEAT, CHUNK), C3 = ccdiv(kETA, CHUNK);
constexpr int CBTOT = C0 + C1 + C2 + C3;

struct TyInfo {
  const int* ep; int E; int nb; int bhoff; int boff; int eoff; int cb;
};

__device__ __forceinline__ TyInfo ty_from_block(
    int blk, const int* e0, const int* e1, const int* e2, const int* e3) {
  TyInfo ti;
  if (blk < C0) { ti = {e0, kEPT, NB0, 0, 0, 0, blk}; }
  else if (blk < C0 + C1) {
    ti = {e1, kETP, NB1, NB0, NB0 + 1, kEPT, blk - C0};
  } else if (blk < C0 + C1 + C2) {
    ti = {e2, kEAT, NB2, NB0 + NB1, NB0 + NB1 + 2, kEPT + kETP, blk - C0 - C1};
  } else {
    ti = {e3, kETA, NB3, NB0 + NB1 + NB2, NB0 + NB1 + NB2 + 3,
          kEPT + kETP + kEAT, blk - C0 - C1 - C2};
  }
  return ti;
}

__global__ __launch_bounds__(256) void bucket_hist(
    const int* __restrict__ e0, const int* __restrict__ e1,
    const int* __restrict__ e2, const int* __restrict__ e3,
    int* __restrict__ bh) {
  __shared__ int h[NB0];
  TyInfo ti = ty_from_block(blockIdx.x, e0, e1, e2, e3);
  const int* dstp = ti.ep + ti.E;
  for (int i = threadIdx.x; i < ti.nb; i += 256) h[i] = 0;
  __syncthreads();
  int jend = min(ti.E, (ti.cb + 1) * CHUNK);
  for (int j = ti.cb * CHUNK + threadIdx.x; j < jend; j += 256)
    atomicAdd(&h[dstp[j] >> 8], 1);
  __syncthreads();
  for (int i = threadIdx.x; i < ti.nb; i += 256) {
    int v = h[i];
    if (v) atomicAdd(&bh[ti.bhoff + i], v);
  }
}

__global__ __launch_bounds__(1024) void bucket_scan(const int* __restrict__ bh,
                                                    int* __restrict__ bb,
                                                    int* __restrict__ gcur) {
  __shared__ int s[1024];
  int ty = blockIdx.x;
  int nb = (ty == 0) ? NB0 : (ty == 1) ? NB1 : (ty == 2) ? NB2 : NB3;
  int E = (ty == 0) ? kEPT : (ty == 1) ? kETP : (ty == 2) ? kEAT : kETA;
  int bhoff = (ty == 0) ? 0 : (ty == 1) ? NB0 : (ty == 2) ? NB0 + NB1
                                               : NB0 + NB1 + NB2;
  int boff = bhoff + ty;
  int t = threadIdx.x;
  int v = (t < nb) ? bh[bhoff + t] : 0;
  s[t] = v;
  __syncthreads();
  for (int o = 1; o < 1024; o <<= 1) {
    int x = (t >= o) ? s[t - o] : 0;
    __syncthreads();
    s[t] += x;
    __syncthreads();
  }
  if (t < nb) {
    int ex = s[t] - v;
    bb[boff + t] = ex;
    gcur[bhoff + t] = ex;
  }
  if (t == 0) bb[boff + nb] = E;
}

__global__ __launch_bounds__(256) void bin_edges(
    const int* __restrict__ e0, const int* __restrict__ e1,
    const int* __restrict__ e2, const int* __restrict__ e3,
    int* __restrict__ gcur, int* __restrict__ bin) {
  __shared__ int h[NB0];
  __shared__ int hb[NB0];
  TyInfo ti = ty_from_block(blockIdx.x, e0, e1, e2, e3);
  const int* dstp = ti.ep + ti.E;
  for (int i = threadIdx.x; i < ti.nb; i += 256) h[i] = 0;
  __syncthreads();
  int j0 = ti.cb * CHUNK + threadIdx.x;
  int jend = min(ti.E, (ti.cb + 1) * CHUNK);
  for (int j = j0; j < jend; j += 256) atomicAdd(&h[dstp[j] >> 8], 1);
  __syncthreads();
  for (int i = threadIdx.x; i < ti.nb; i += 256) {
    int v = h[i];
    hb[i] = v ? atomicAdd(&gcur[ti.bhoff + i], v) : 0;
    h[i] = 0;
  }
  __syncthreads();
  for (int j = j0; j < jend; j += 256) {
    int d = dstp[j];
    int b = d >> 8;
    int pos = hb[b] + atomicAdd(&h[b], 1);
    bin[ti.eoff + pos] = ti.ep[j] | ((d & 255) << 24);
  }
}

__global__ __launch_bounds__(256) void fine_fill(
    const int* __restrict__ bin, const int* __restrict__ bb,
    int* __restrict__ rp0, int* __restrict__ rp1, int* __restrict__ rp2,
    int* __restrict__ rp3, int* __restrict__ co0, int* __restrict__ co1,
    int* __restrict__ co2, int* __restrict__ co3) {
  __shared__ int cnt[256];
  __shared__ int excl[256];
  int b = blockIdx.x;
  int ty, lb;
  if (b < NB0) { ty = 0; lb = b; }
  else if (b < NB0 + NB1) { ty = 1; lb = b - NB0; }
  else if (b < NB0 + NB1 + NB2) { ty = 2; lb = b - NB0 - NB1; }
  else { ty = 3; lb = b - NB0 - NB1 - NB2; }
  int nb = (ty == 0) ? NB0 : (ty == 1) ? NB1 : (ty == 2) ? NB2 : NB3;
  int N = (ty == 0) ? kNT : (ty == 1) ? kNP : (ty == 2) ? kNT : kNA;
  int E = (ty == 0) ? kEPT : (ty == 1) ? kETP : (ty == 2) ? kEAT : kETA;
  int bhoff = (ty == 0) ? 0 : (ty == 1) ? NB0 : (ty == 2) ? NB0 + NB1
                                               : NB0 + NB1 + NB2;
  int boff = bhoff + ty;
  int eoff = (ty == 0) ? 0 : (ty == 1) ? kEPT : (ty == 2) ? kEPT + kETP
                                                : kEPT + kETP + kEAT;
  int* rp = (ty == 0) ? rp0 : (ty == 1) ? rp1 : (ty == 2) ? rp2 : rp3;
  int* col = (ty == 0) ? co0 : (ty == 1) ? co1 : (ty == 2) ? co2 : co3;

  int base = bb[boff + lb];
  int end = bb[boff + lb + 1];
  int t = threadIdx.x;
  cnt[t] = 0;
  __syncthreads();
  for (int j = base + t; j < end; j += 256)
    atomicAdd(&cnt[(bin[eoff + j] >> 24) & 255], 1);
  __syncthreads();
  int v = cnt[t];
  excl[t] = v;
  __syncthreads();
  for (int o = 1; o < 256; o <<= 1) {
    int x = (t >= o) ? excl[t - o] : 0;
    __syncthreads();
    excl[t] += x;
    __syncthreads();
  }
  excl[t] -= v;
  cnt[t] = 0;
  __syncthreads();
  int node = (lb << 8) + t;
  if (node < N) rp[node] = base + excl[t];
  if (lb == nb - 1 && t == 0) rp[N] = E;
  for (int j = base + t; j < end; j += 256) {
    int v2 = bin[eoff + j];
    int l = (v2 >> 24) & 255;
    int pos = base + excl[l] + atomicAdd(&cnt[l], 1);
    col[pos] = v2 & 0xFFFFFF;
  }
}

// ---------------- gathers (4-edge batched loads, fp32 acc, bf16 out) ---------

__device__ __forceinline__ void gacc(const short8* __restrict__ Xv, int ldx8,
                                     int off8c, const int* __restrict__ col,
                                     int s, int e, float acc[8]) {
  int j = s;
  for (; j + 4 <= e; j += 4) {
    short8 v0 = Xv[(size_t)col[j] * ldx8 + off8c];
    short8 v1 = Xv[(size_t)col[j + 1] * ldx8 + off8c];
    short8 v2 = Xv[(size_t)col[j + 2] * ldx8 + off8c];
    short8 v3 = Xv[(size_t)col[j + 3] * ldx8 + off8c];
#pragma unroll
    for (int i = 0; i < 8; ++i)
      acc[i] += (bf2f(v0[i]) + bf2f(v1[i])) + (bf2f(v2[i]) + bf2f(v3[i]));
  }
  for (; j < e; ++j) {
    short8 v = Xv[(size_t)col[j] * ldx8 + off8c];
#pragma unroll
    for (int i = 0; i < 8; ++i) acc[i] += bf2f(v[i]);
  }
}

__global__ __launch_bounds__(256) void gather4(
    const short* __restrict__ xpeb, const short* __restrict__ xaeb,
    const short* __restrict__ xtb, const int* __restrict__ rp_pt,
    const int* __restrict__ col_pt, short* __restrict__ aggpt,
    const int* __restrict__ rp_at, const int* __restrict__ col_at,
    short* __restrict__ aggat, const int* __restrict__ rp_tp,
    const int* __restrict__ col_tp, short* __restrict__ aggtp,
    const int* __restrict__ rp_ta, const int* __restrict__ col_ta,
    short* __restrict__ aggta) {
  constexpr int R0 = kNT, R1 = 2 * kNT, R2 = 2 * kNT + kNP,
                R3 = 2 * kNT + kNP + kNA;
  int g = blockIdx.x * 16 + (int)threadIdx.x / 16;
  int c = (int)threadIdx.x % 16;
  const short* X;
  const int* rp;
  const int* col;
  short* out;
  int r;
  if (g < R0) { X = xpeb; rp = rp_pt; col = col_pt; out = aggpt; r = g; }
  else if (g < R1) { X = xaeb; rp = rp_at; col = col_at; out = aggat; r = g - R0; }
  else if (g < R2) { X = xtb; rp = rp_tp; col = col_tp; out = aggtp; r = g - R1; }
  else if (g < R3) { X = xtb; rp = rp_ta; col = col_ta; out = aggta; r = g - R2; }
  else return;
  int s = rp[r], e = rp[r + 1];
  float acc[8] = {0.f, 0.f, 0.f, 0.f, 0.f, 0.f, 0.f, 0.f};
  gacc(reinterpret_cast<const short8*>(X), 16, c, col, s, e, acc);
  float inv = 1.0f / fmaxf((float)(e - s), 1.0f);
  short8 w;
#pragma unroll
  for (int i = 0; i < 8; ++i) w[i] = f2bf(acc[i] * inv);
  reinterpret_cast<short8*>(out)[(size_t)r * 16 + c] = w;
}

__global__ __launch_bounds__(256) void gather_tpta(
    const short* __restrict__ ypab, const int* __restrict__ rp_tp,
    const int* __restrict__ col_tp, short* __restrict__ g_tp,
    const int* __restrict__ rp_ta, const int* __restrict__ col_ta,
    short* __restrict__ g_ta) {
  int g = blockIdx.x * 16 + (int)threadIdx.x / 16;
  int c = (int)threadIdx.x % 16;
  const int* rp;
  const int* col;
  short* out;
  int r, off8;
  if (g < kNP) { rp = rp_tp; col = col_tp; out = g_tp; r = g; off8 = 0; }
  else if (g < kNP + kNA) { rp = rp_ta; col = col_ta; out = g_ta; r = g - kNP; off8 = 16; }
  else return;
  int s = rp[r], e = rp[r + 1];
  float acc[8] = {0.f, 0.f, 0.f, 0.f, 0.f, 0.f, 0.f, 0.f};
  gacc(reinterpret_cast<const short8*>(ypab), 32, off8 + c, col, s, e, acc);
  float inv = 1.0f / fmaxf((float)(e - s), 1.0f);
  short8 w;
#pragma unroll
  for (int i = 0; i < 8; ++i) w[i] = f2bf(acc[i] * inv);
  reinterpret_cast<short8*>(out)[(size_t)r * 16 + c] = w;
}

__global__ __launch_bounds__(256) void gather2_b(
    const short* __restrict__ X1, const int* __restrict__ rp1,
    const int* __restrict__ col1, const short* __restrict__ X2,
    const int* __restrict__ rp2, const int* __restrict__ col2,
    short* __restrict__ out, int N) {
  int g = blockIdx.x * 16 + (int)threadIdx.x / 16;
  int c = (int)threadIdx.x % 16;
  if (g >= N) return;
  float tot[8] = {0.f, 0.f, 0.f, 0.f, 0.f, 0.f, 0.f, 0.f};
  {
    int s = rp1[g], e = rp1[g + 1];
    float a[8] = {0.f, 0.f, 0.f, 0.f, 0.f, 0.f, 0.f, 0.f};
    gacc(reinterpret_cast<const short8*>(X1), 16, c, col1, s, e, a);
    float inv = 1.0f / fmaxf((float)(e - s), 1.0f);
#pragma unroll
    for (int i = 0; i < 8; ++i) tot[i] += a[i] * inv;
  }
  {
    int s = rp2[g], e = rp2[g + 1];
    float a[8] = {0.f, 0.f, 0.f, 0.f, 0.f, 0.f, 0.f, 0.f};
    gacc(reinterpret_cast<const short8*>(X2), 16, c, col2, s, e, a);
    float inv = 1.0f / fmaxf((float)(e - s), 1.0f);
#pragma unroll
    for (int i = 0; i < 8; ++i) tot[i] += a[i] * inv;
  }
  short8 w;
#pragma unroll
  for (int i = 0; i < 8; ++i) w[i] = f2bf(tot[i]);
  reinterpret_cast<short8*>(out)[(size_t)g * 16 + c] = w;
}

// ------- MFMA GEMM (WC=8, no duplicated B loads) — p_out/a_out ---------------
// C fp32 = A@B + bias + bf2f(add0);  A [N][256], B frag D=128 K=256.

struct GemmP {
  const short* A0;
  const short* B0;
  const float* bias; const short* add0;
  float* Cf; int N;
};

__device__ __forceinline__ void gemm_core(const GemmP& p, int blk) {
  constexpr int K = 256;
  constexpr int KCH = K / 32;  // 8

  __shared__ short As[2][64 * 128];

  const int tid = threadIdx.x;
  const int lane = tid & 63;
  const int w = tid >> 6;
  const int lr = lane & 15;
  const int ls = lane >> 4;
  const int n0 = blk * 64;
  const int N = p.N;

  auto stage = [&](int buf, int kc) {
#pragma unroll
    for (int it = 0; it < 2; ++it) {
      int u = it * 512 + w * 64 + lane;
      int row = u >> 4;
      int c8s = u & 15;
      int n = n0 + row;
      if (n >= N) n = N - 1;
      const short* g = p.A0 + (size_t)n * K + kc + ((c8s ^ (row & 7)) << 3);
      short* l = &As[buf][(it * 512 + w * 64) * 8];
      __builtin_amdgcn_global_load_lds(
          (const __attribute__((address_space(1))) void*)g,
          (__attribute__((address_space(3))) void*)l, 16, 0, 0);
    }
  };

  f32x4 acc[4] = {};

  stage(0, 0);
  __syncthreads();

#pragma unroll
  for (int c = 0; c < 2; ++c) {
    const int buf = c & 1;
    const int kc32 = c * 4;
    short8 bfr[4];
#pragma unroll
    for (int kk = 0; kk < 4; ++kk)
      bfr[kk] = *reinterpret_cast<const short8*>(
          p.B0 + ((size_t)(w * KCH + kc32 + kk) * 64 + lane) * 8);
    __builtin_amdgcn_sched_barrier(0);
    if (c == 0) stage(1, 128);
    __builtin_amdgcn_sched_barrier(0);
#pragma unroll
    for (int kk = 0; kk < 4; ++kk) {
#pragma unroll
      for (int tm = 0; tm < 4; ++tm) {
        int row = tm * 16 + lr;
        short8 af = *reinterpret_cast<const short8*>(
            &As[buf][(row * 128 + (kk * 4 + ls) * 8) ^ ((row & 7) << 3)]);
        acc[tm] = __builtin_amdgcn_mfma_f32_16x16x32_bf16(af, bfr[kk], acc[tm],
                                                          0, 0, 0);
      }
    }
    __syncthreads();
  }

  int colg = w * 16 + lr;
  float bv = p.bias[colg];
#pragma unroll
  for (int tm = 0; tm < 4; ++tm) {
#pragma unroll
    for (int r = 0; r < 4; ++r) {
      int n = n0 + tm * 16 + ls * 4 + r;
      if (n < N) {
        float v = acc[tm][r] + bv + bf2f(p.add0[(size_t)n * 128 + colg]);
        p.Cf[(size_t)n * 128 + colg] = v;
      }
    }
  }
}

__global__ __launch_bounds__(512, 8) void mfma_gemm_pair(GemmP pa, GemmP pb,
                                                         int split) {
  if ((int)blockIdx.x < split)
    gemm_core(pa, blockIdx.x);
  else
    gemm_core(pb, blockIdx.x - split);
}

// ------- MEGA (WC=8): conv1 GEMM -> LDS tile -> fused K=256 GEMM -------------
// Phase A: H = relu(sum_a A_a @ Wa_a + abias) -> LDS [64][256] (+Astore if !TRACK)
// Phase B TRACK: D=384 GEMM vs wdual: cols 0-127 -> t_out(+gt+bc), 128-383 -> ypab
// Phase B pa:    D=128 GEMM vs Wb -> B1b (ypb/yab)

struct MegaP {
  const short* A0; const short* A1; const short* A2;
  const short* Wa0; const short* Wa1; const short* Wa2;  // frag D=256,K=128
  const float* abias;
  short* Astore;         // pa: p1b/a1b
  const short* Wb;       // TRACK: wdual (3xD=128,K=256); pa: w2l seg
  const float* bcmb;     // TRACK: bc
  const short* gt;       // TRACK
  float* tout;           // TRACK
  short* ypab;           // TRACK
  short* B1b;            // pa
  int N;
};

template <int NA, bool TRACK>
__device__ __forceinline__ void mega_core(const MegaP& p, int blk) {
  constexpr int TNB = TRACK ? 3 : 1;

  __shared__ short As[2][64 * 128];
  short* t1s = &As[0][0];  // [64][256] swizzled after phase A

  const int tid = threadIdx.x;
  const int lane = tid & 63;
  const int w = tid >> 6;  // 0..7
  const int lr = lane & 15;
  const int ls = lane >> 4;
  const int n0 = blk * 64;
  const int N = p.N;

  const short* Ap[3] = {p.A0, p.A1, p.A2};
  const short* Wp[3] = {p.Wa0, p.Wa1, p.Wa2};

  auto stage = [&](int buf, int a) {
#pragma unroll
    for (int it = 0; it < 2; ++it) {
      int u = it * 512 + w * 64 + lane;
      int row = u >> 4;
      int c8s = u & 15;
      int n = n0 + row;
      if (n >= N) n = N - 1;
      const short* g = Ap[a] + (size_t)n * 128 + ((c8s ^ (row & 7)) << 3);
      short* l = &As[buf][(it * 512 + w * 64) * 8];
      __builtin_amdgcn_global_load_lds(
          (const __attribute__((address_space(1))) void*)g,
          (__attribute__((address_space(3))) void*)l, 16, 0, 0);
    }
  };

  // ---- phase A (DOUT=256, WC=8, TN=2, TM=4) ----
  f32x4 acc[4][2] = {};
  stage(0, 0);
  __syncthreads();
#pragma unroll
  for (int c = 0; c < NA; ++c) {
    const int buf = c & 1;
    const short* Ba = Wp[c];
    short8 bfr[4][2];
#pragma unroll
    for (int kk = 0; kk < 4; ++kk)
#pragma unroll
      for (int tn = 0; tn < 2; ++tn)
        bfr[kk][tn] = *reinterpret_cast<const short8*>(
            Ba + ((size_t)((w * 2 + tn) * 4 + kk) * 64 + lane) * 8);
    __builtin_amdgcn_sched_barrier(0);
    if (c + 1 < NA) stage(buf ^ 1, c + 1);
    __builtin_amdgcn_sched_barrier(0);
#pragma unroll
    for (int kk = 0; kk < 4; ++kk) {
#pragma unroll
      for (int tm = 0; tm < 4; ++tm) {
        int row = tm * 16 + lr;
        short8 af = *reinterpret_cast<const short8*>(
            &As[buf][(row * 128 + (kk * 4 + ls) * 8) ^ ((row & 7) << 3)]);
#pragma unroll
        for (int tn = 0; tn < 2; ++tn)
          acc[tm][tn] = __builtin_amdgcn_mfma_f32_16x16x32_bf16(
              af, bfr[kk][tn], acc[tm][tn], 0, 0, 0);
      }
    }
    __syncthreads();
  }

  // ---- phase A epilogue: relu+bias -> bf16 LDS tile (+ optional global) ----
#pragma unroll
  for (int tm = 0; tm < 4; ++tm) {
#pragma unroll
    for (int tn = 0; tn < 2; ++tn) {
      int colg = w * 32 + tn * 16 + lr;
      float bv = p.abias[colg];
#pragma unroll
      for (int r = 0; r < 4; ++r) {
        int row = tm * 16 + ls * 4 + r;
        int n = n0 + row;
        float v = fmaxf(acc[tm][tn][r] + bv, 0.f);
        short b = f2bf(v);
        t1s[row * 256 + (colg ^ ((row & 7) << 3))] = b;
        if constexpr (!TRACK) {
          if (n < N) p.Astore[(size_t)n * 256 + colg] = b;
        }
      }
    }
  }
  __syncthreads();

  // ---- phase B: K=256 from LDS, DOUT = TNB*128 over 8 waves ----
  f32x4 bacc[4][TNB] = {};
#pragma unroll
  for (int kk = 0; kk < 8; ++kk) {
    short8 bfb[TNB];
#pragma unroll
    for (int tn = 0; tn < TNB; ++tn)
      bfb[tn] = *reinterpret_cast<const short8*>(
          p.Wb + ((size_t)((w * TNB + tn) * 8 + kk) * 64 + lane) * 8);
#pragma unroll
    for (int tm = 0; tm < 4; ++tm) {
      int row = tm * 16 + lr;
      short8 af = *reinterpret_cast<const short8*>(
          &t1s[(row * 256 + kk * 32 + ls * 8) ^ ((row & 7) << 3)]);
#pragma unroll
      for (int tn = 0; tn < TNB; ++tn)
        bacc[tm][tn] = __builtin_amdgcn_mfma_f32_16x16x32_bf16(
            af, bfb[tn], bacc[tm][tn], 0, 0, 0);
    }
  }
  // phase B epilogue
#pragma unroll
  for (int tm = 0; tm < 4; ++tm) {
#pragma unroll
    for (int tn = 0; tn < TNB; ++tn) {
      int colg = (w * TNB + tn) * 16 + lr;
#pragma unroll
      for (int r = 0; r < 4; ++r) {
        int n = n0 + tm * 16 + ls * 4 + r;
        if (n < N) {
          float v = bacc[tm][tn][r];
          if constexpr (TRACK) {
            if (colg < 128) {
              v += p.bcmb[colg] + bf2f(p.gt[(size_t)n * 128 + colg]);
              p.tout[(size_t)n * 128 + colg] = v;
            } else {
              p.ypab[(size_t)n * 256 + (colg - 128)] = f2bf(v);
            }
          } else {
            p.B1b[(size_t)n * 128 + colg] = f2bf(v);
          }
        }
      }
    }
  }
}

template <int NA, bool TRACK>
__global__ __launch_bounds__(512, 8) void mega_kernel(MegaP p) {
  mega_core<NA, TRACK>(p, blockIdx.x);
}

template <int NA, bool TRACK>
__global__ __launch_bounds__(512, 8) void mega_pair(MegaP pa, MegaP pb,
                                                    int split) {
  if ((int)blockIdx.x < split)
    mega_core<NA, TRACK>(pa, blockIdx.x);
  else
    mega_core<NA, TRACK>(pb, blockIdx.x - split);
}

}  // namespace

extern "C" void kernel_launch(void* const* d_in, const int* in_sizes, int n_in,
                              void* d_out, int out_size, void* d_ws,
                              size_t ws_size, hipStream_t stream) {
  const float* x_p   = (const float*)d_in[0];
  const float* x_t   = (const float*)d_in[1];
  const float* x_a   = (const float*)d_in[2];
  const float* emb_p = (const float*)d_in[3];
  const float* emb_a = (const float*)d_in[4];
  const float* W1l   = (const float*)d_in[5];
  const float* b1    = (const float*)d_in[6];
  const float* W1r   = (const float*)d_in[7];
  const float* W2l   = (const float*)d_in[8];
  const float* b2    = (const float*)d_in[9];
  const float* W2r   = (const float*)d_in[10];
  const float* Wres  = (const float*)d_in[11];
  const float* bres  = (const float*)d_in[12];
  const int* e_pt = (const int*)d_in[13];
  const int* e_tp = (const int*)d_in[14];
  const int* e_at = (const int*)d_in[15];
  const int* e_ta = (const int*)d_in[16];
  (void)in_sizes; (void)n_in; (void)out_size; (void)ws_size;

  float* out = (float*)d_out;
  float* p_out = out;
  float* t_out = out + (size_t)kNP * DO;
  float* a_out = out + (size_t)(kNP + kNT) * DO;

  char* base = (char*)d_ws;
  size_t off = 0;
  auto alloc = [&](size_t bytes) {
    off = (off + 255) & ~size_t(255);
    void* p = base + off;
    off += bytes;
    return p;
  };

  short* ypab  = (short*)alloc((size_t)kNT * DH * 2);
  short* gt    = (short*)alloc((size_t)kNT * DO * 2);
  short* p1b   = (short*)alloc((size_t)kNP * DH * 2);
  short* a1b   = (short*)alloc((size_t)kNA * DH * 2);
  short* aggpt = (short*)alloc((size_t)kNT * DIN * 2);
  short* aggat = (short*)alloc((size_t)kNT * DIN * 2);
  short* aggtp = (short*)alloc((size_t)kNP * DIN * 2);
  short* aggta = (short*)alloc((size_t)kNA * DIN * 2);
  short* xpeb  = (short*)alloc((size_t)kNP * DIN * 2);
  short* xaeb  = (short*)alloc((size_t)kNA * DIN * 2);
  short* xtb   = (short*)alloc((size_t)kNT * DIN * 2);
  short* ypb   = (short*)alloc((size_t)kNP * DO * 2);
  short* yab   = (short*)alloc((size_t)kNA * DO * 2);
  short* g_tp  = (short*)alloc((size_t)kNP * DO * 2);
  short* g_ta  = (short*)alloc((size_t)kNA * DO * 2);
  short* w1l_rm  = (short*)alloc(4 * per1 * 2);
  short* w1r_rm  = (short*)alloc(4 * per1 * 2);
  short* w1rc_rm = (short*)alloc(per1 * 2);
  short* w2l_rm  = (short*)alloc(4 * per2 * 2);
  short* wc_rm   = (short*)alloc(3 * per2 * 2);
  short* w1lb   = (short*)alloc(4 * per1 * 2);
  short* w1rb   = (short*)alloc(4 * per1 * 2);
  short* w1rcb  = (short*)alloc(per1 * 2);
  short* w2lb   = (short*)alloc(4 * per2 * 2);
  short* wcb    = (short*)alloc(3 * per2 * 2);
  short* wdual  = (short*)alloc(3 * per2 * 2);
  float* bc     = (float*)alloc(3 * DO * 4);
  float* b1ct   = (float*)alloc(DH * 4);

  int* rp_pt  = (int*)alloc((kNT + 1) * 4);
  int* rp_tp  = (int*)alloc((kNP + 1) * 4);
  int* rp_at  = (int*)alloc((kNT + 1) * 4);
  int* rp_ta  = (int*)alloc((kNA + 1) * 4);
  int* col_pt = (int*)alloc(kEPT * 4);
  int* col_tp = (int*)alloc(kETP * 4);
  int* col_at = (int*)alloc(kEAT * 4);
  int* col_ta = (int*)alloc(kETA * 4);
  int* bh     = (int*)alloc(NBTOT * 4);
  int* bb     = (int*)alloc(BBTOT * 4);
  int* gcur   = (int*)alloc(NBTOT * 4);
  int* bin    = (int*)alloc((size_t)(kEPT + kETP + kEAT + kETA) * 4);

  // ---- 0. fused converts ----
  {
    int tot = kNP * DIN / 8 + kNA * DIN / 8 + kNT * DIN / 8;
    cvt_all<<<cdiv(tot, 256), 256, 0, stream>>>(x_p, emb_p, xpeb, x_a, emb_a,
                                                xaeb, x_t, xtb);
  }

  // ---- 1. fused weight prep + fragment swizzle ----
  {
    int tot = 4 * per1 + 4 * per1 + per1 + 4 * per2 + 3 * per2 + DH;
    prep_all<<<cdiv(tot, 256), 256, 0, stream>>>(
        W1l, W1r, W2l, Wres, W2r, bres, b2, b1, w1l_rm, w1r_rm, w1rc_rm,
        w2l_rm, wc_rm, bc, b1ct);
    swizzle_all<<<cdiv(77824, 256), 256, 0, stream>>>(
        w1l_rm, w1lb, w1r_rm, w1rb, w1rc_rm, w1rcb, w2l_rm, w2lb, wc_rm, wcb,
        wdual);
  }

  // ---- 2. CSR build (bucketed counting sort) ----
  hipMemsetAsync(bh, 0, NBTOT * 4, stream);
  bucket_hist<<<CBTOT, 256, 0, stream>>>(e_pt, e_tp, e_at, e_ta, bh);
  bucket_scan<<<4, 1024, 0, stream>>>(bh, bb, gcur);
  bin_edges<<<CBTOT, 256, 0, stream>>>(e_pt, e_tp, e_at, e_ta, gcur, bin);
  fine_fill<<<NBTOT, 256, 0, stream>>>(bin, bb, rp_pt, rp_tp, rp_at, rp_ta,
                                       col_pt, col_tp, col_at, col_ta);

  // ---- 3. conv1 gathers (one launch) ----
  gather4<<<cdiv(2 * kNT + kNP + kNA, 16), 256, 0, stream>>>(
      xpeb, xaeb, xtb, rp_pt, col_pt, aggpt, rp_at, col_at, aggat, rp_tp,
      col_tp, aggtp, rp_ta, col_ta, aggta);

  // ---- 4. mega_pa: conv1 p/a GEMM + fused down-projection ----
  {
    MegaP mp = {aggtp, xpeb, nullptr, w1lb + 1 * per1, w1rb + 1 * per1,
                nullptr, b1 + 1 * DH, p1b, w2lb + 0 * per2, nullptr, nullptr,
                nullptr, nullptr, ypb, kNP};
    MegaP ma = {aggta, xaeb, nullptr, w1lb + 3 * per1, w1rb + 3 * per1,
                nullptr, b1 + 3 * DH, a1b, w2lb + 2 * per2, nullptr, nullptr,
                nullptr, nullptr, yab, kNA};
    int split = cdiv(kNP, 64);
    mega_pair<2, false>
        <<<split + cdiv(kNA, 64), 512, 0, stream>>>(mp, ma, split);
  }

  // ---- 5. gt = mean_pt(y_p) + mean_at(y_a) ----
  gather2_b<<<cdiv(kNT, 16), 256, 0, stream>>>(ypb, rp_pt, col_pt, yab, rp_at,
                                               col_at, gt, kNT);

  // ---- 6. mega_t: conv1-t GEMM + fused D=384 {t_out, ypab} ----
  {
    MegaP mt = {aggpt, aggat, xtb, w1lb + 0 * per1, w1lb + 2 * per1, w1rcb,
                b1ct, nullptr, wdual, bc + 0 * DO, gt, t_out, ypab, nullptr,
                kNT};
    mega_kernel<3, true><<<cdiv(kNT, 64), 512, 0, stream>>>(mt);
  }

  // ---- 7. conv2 tp/ta gathers ----
  gather_tpta<<<cdiv(kNP + kNA, 16), 256, 0, stream>>>(
      ypab, rp_tp, col_tp, g_tp, rp_ta, col_ta, g_ta);

  // ---- 8. p_out / a_out (paired, WC=8) ----
  {
    GemmP pp = {p1b, wcb + per2, bc + DO, g_tp, p_out, kNP};
    GemmP pa = {a1b, wcb + 2 * per2, bc + 2 * DO, g_ta, a_out, kNA};
    int split = cdiv(kNP, 64);
    mfma_gemm_pair<<<split + cdiv(kNA, 64), 512, 0, stream>>>(pp, pa, split);
  }
}

// Round 16
// 666.200 us; speedup vs baseline: 2.0289x; 2.0289x over previous
//
#include <hip/hip_runtime.h>

namespace {

typedef __attribute__((ext_vector_type(8))) short short8;
typedef __attribute__((ext_vector_type(4))) float f32x4;

constexpr int kNP = 50000, kNT = 200000, kNA = 20000;
constexpr int kEPT = 1000000, kETP = 1000000, kEAT = 400000, kETA = 400000;
constexpr int DIN = 128, DH = 256, DO = 128;
constexpr int per1 = DIN * DH;  // 32768
constexpr int per2 = DH * DO;   // 32768

__device__ __forceinline__ float bf2f(short u) {
  union { unsigned int i; float f; } c;
  c.i = ((unsigned int)(unsigned short)u) << 16;
  return c.f;
}
__device__ __forceinline__ short f2bf(float f) {
  union { float f; unsigned int i; } c;
  c.f = f;
  unsigned int r = c.i + 0x7fffu + ((c.i >> 16) & 1u);  // RNE
  return (short)(r >> 16);
}

inline int cdiv(int a, int b) { return (a + b - 1) / b; }
constexpr int ccdiv(int a, int b) { return (a + b - 1) / b; }

// ---------------- fused convert: xpe, xae, xt -> bf16 ----------------

__global__ __launch_bounds__(256) void cvt_all(
    const float* __restrict__ x_p, const float* __restrict__ emb_p,
    short* __restrict__ xpeb, const float* __restrict__ x_a,
    const float* __restrict__ emb_a, short* __restrict__ xaeb,
    const float* __restrict__ x_t, short* __restrict__ xtb) {
  constexpr int N0 = kNP * DIN / 8;
  constexpr int N1 = N0 + kNA * DIN / 8;
  constexpr int N2 = N1 + kNT * DIN / 8;
  int g = blockIdx.x * 256 + threadIdx.x;
  const float* a;
  const float* b = nullptr;
  short* o;
  int i;
  if (g < N0) { a = x_p; b = emb_p; o = xpeb; i = g; }
  else if (g < N1) { a = x_a; b = emb_a; o = xaeb; i = g - N0; }
  else if (g < N2) { a = x_t; o = xtb; i = g - N1; }
  else return;
  const float4* a4 = reinterpret_cast<const float4*>(a);
  float4 x0 = a4[2 * i], x1 = a4[2 * i + 1];
  if (b != nullptr) {
    const float4* b4 = reinterpret_cast<const float4*>(b);
    float4 y0 = b4[2 * i], y1 = b4[2 * i + 1];
    x0.x += y0.x; x0.y += y0.y; x0.z += y0.z; x0.w += y0.w;
    x1.x += y1.x; x1.y += y1.y; x1.z += y1.z; x1.w += y1.w;
  }
  short8 w;
  w[0] = f2bf(x0.x); w[1] = f2bf(x0.y); w[2] = f2bf(x0.z); w[3] = f2bf(x0.w);
  w[4] = f2bf(x1.x); w[5] = f2bf(x1.y); w[6] = f2bf(x1.z); w[7] = f2bf(x1.w);
  reinterpret_cast<short8*>(o)[i] = w;
}

// ---------------- fused weight prep (row-major bf16 + fp32 biases) -----------

__global__ __launch_bounds__(256) void prep_all(
    const float* __restrict__ W1l, const float* __restrict__ W1r,
    const float* __restrict__ W2l, const float* __restrict__ Wres,
    const float* __restrict__ W2r, const float* __restrict__ bres,
    const float* __restrict__ b2, const float* __restrict__ b1,
    short* __restrict__ w1l_rm, short* __restrict__ w1r_rm,
    short* __restrict__ w1rc_rm, short* __restrict__ w2l_rm,
    short* __restrict__ wc_rm, float* __restrict__ bc,
    float* __restrict__ b1ct) {
  constexpr int P0 = 4 * per1;
  constexpr int P1 = P0 + 4 * per1;
  constexpr int P2 = P1 + per1;
  constexpr int P3 = P2 + 4 * per2;
  constexpr int P4 = P3 + 3 * per2;
  constexpr int P5 = P4 + DH;
  int g = blockIdx.x * 256 + threadIdx.x;
  if (g < P0) {
    int e = g / per1;
    float s = (e == 0 || e == 2) ? 0.5f : 1.0f;
    w1l_rm[g] = f2bf(W1l[g] * s);
  } else if (g < P1) {
    int l = g - P0;
    w1r_rm[l] = f2bf(W1r[l]);
  } else if (g < P2) {
    int l = g - P1;
    w1rc_rm[l] = f2bf(0.5f * (W1r[l] + W1r[2 * per1 + l]));
  } else if (g < P3) {
    int l = g - P2;
    int e = l / per2;
    float s = (e == 0 || e == 2) ? 0.5f : 1.0f;
    w2l_rm[l] = f2bf(W2l[l] * s);
  } else if (g < P4) {
    int l = g - P3;
    {
      int b = l / per2;
      int idx = l - b * per2;
      int resIdx = (b == 0) ? 1 : (b == 1) ? 0 : 2;
      float v = Wres[(size_t)resIdx * per2 + idx];
      if (b == 0)
        v += 0.5f * (W2r[idx] + W2r[(size_t)2 * per2 + idx]);
      else if (b == 1)
        v += W2r[(size_t)1 * per2 + idx];
      else
        v += W2r[(size_t)3 * per2 + idx];
      wc_rm[l] = f2bf(v);
    }
    if (l < 3 * DO) {
      int b = l / DO;
      int o = l - b * DO;
      int resIdx = (b == 0) ? 1 : (b == 1) ? 0 : 2;
      float v = bres[resIdx * DO + o];
      if (b == 0)
        v += 0.5f * (b2[0 * DO + o] + b2[2 * DO + o]);
      else if (b == 1)
        v += b2[1 * DO + o];
      else
        v += b2[3 * DO + o];
      bc[l] = v;
    }
  } else if (g < P5) {
    int l = g - P4;
    b1ct[l] = 0.5f * (b1[l] + b1[2 * DH + l]);
  }
}

// ---------------- fragment swizzle (all weights, one launch) ------------------
// bf16 [D][Kk] row-major -> [D/16][Kk/32][lane=ls*16+lr][8]

__device__ __forceinline__ void swz1(const short* __restrict__ in,
                                     short* __restrict__ out, int t, int D,
                                     int Kk) {
  int kch = Kk / 32;
  int per8 = D * Kk / 8;
  int m = t / per8;
  int tt = t - m * per8;
  int cg = tt / (kch * 64);
  int r1 = tt - cg * kch * 64;
  int kc = r1 >> 6;
  int lane = r1 & 63;
  int ls = lane >> 4, lr = lane & 15;
  const short* src = in + (size_t)m * D * Kk + (size_t)(cg * 16 + lr) * Kk +
                     kc * 32 + ls * 8;
  short8 v = *reinterpret_cast<const short8*>(src);
  reinterpret_cast<short8*>(out + (size_t)m * D * Kk)[tt] = v;
}

__global__ __launch_bounds__(256) void swizzle_all(
    const short* __restrict__ w1l_rm, short* __restrict__ w1lb,
    const short* __restrict__ w1r_rm, short* __restrict__ w1rb,
    const short* __restrict__ w1rc_rm, short* __restrict__ w1rcb,
    const short* __restrict__ w2l_rm, short* __restrict__ w2lb,
    const short* __restrict__ wc_rm, short* __restrict__ wcb,
    short* __restrict__ wdual) {
  constexpr int S0 = 4 * per1 / 8;         // 16384
  constexpr int S1 = S0 + 4 * per1 / 8;    // 32768
  constexpr int S2 = S1 + per1 / 8;        // 36864
  constexpr int S3 = S2 + 4 * per2 / 8;    // 53248
  constexpr int S4 = S3 + 3 * per2 / 8;    // 65536
  constexpr int S5 = S4 + per2 / 8;        // 69632
  constexpr int S6 = S5 + per2 / 8;        // 73728
  constexpr int S7 = S6 + per2 / 8;        // 77824
  int g = blockIdx.x * 256 + threadIdx.x;
  if (g < S0) swz1(w1l_rm, w1lb, g, DH, DIN);
  else if (g < S1) swz1(w1r_rm, w1rb, g - S0, DH, DIN);
  else if (g < S2) swz1(w1rc_rm, w1rcb, g - S1, DH, DIN);
  else if (g < S3) swz1(w2l_rm, w2lb, g - S2, DO, DH);
  else if (g < S4) swz1(wc_rm, wcb, g - S3, DO, DH);
  else if (g < S5) swz1(wc_rm, wdual, g - S4, DO, DH);                 // Wc0
  else if (g < S6) swz1(w2l_rm + per2, wdual + per2, g - S5, DO, DH);  // W2l1
  else if (g < S7) swz1(w2l_rm + 3 * per2, wdual + 2 * per2, g - S6, DO, DH);
}

// ---------------- CSR build v2: bucketed counting sort ----------------

constexpr int NB0 = ccdiv(kNT, 256);
constexpr int NB1 = ccdiv(kNP, 256);
constexpr int NB2 = ccdiv(kNT, 256);
constexpr int NB3 = ccdiv(kNA, 256);
constexpr int NBTOT = NB0 + NB1 + NB2 + NB3;
constexpr int BBTOT = NBTOT + 4;
constexpr int CHUNK = 16384;
constexpr int C0 = ccdiv(kEPT, CHUNK), C1 = ccdiv(kETP, CHUNK),
              C2 = ccdiv(kEAT, CHUNK), C3 = ccdiv(kETA, CHUNK);
constexpr int CBTOT = C0 + C1 + C2 + C3;

struct TyInfo {
  const int* ep; int E; int nb; int bhoff; int boff; int eoff; int cb;
};

__device__ __forceinline__ TyInfo ty_from_block(
    int blk, const int* e0, const int* e1, const int* e2, const int* e3) {
  TyInfo ti;
  if (blk < C0) { ti = {e0, kEPT, NB0, 0, 0, 0, blk}; }
  else if (blk < C0 + C1) {
    ti = {e1, kETP, NB1, NB0, NB0 + 1, kEPT, blk - C0};
  } else if (blk < C0 + C1 + C2) {
    ti = {e2, kEAT, NB2, NB0 + NB1, NB0 + NB1 + 2, kEPT + kETP, blk - C0 - C1};
  } else {
    ti = {e3, kETA, NB3, NB0 + NB1 + NB2, NB0 + NB1 + NB2 + 3,
          kEPT + kETP + kEAT, blk - C0 - C1 - C2};
  }
  return ti;
}

__global__ __launch_bounds__(256) void bucket_hist(
    const int* __restrict__ e0, const int* __restrict__ e1,
    const int* __restrict__ e2, const int* __restrict__ e3,
    int* __restrict__ bh) {
  __shared__ int h[NB0];
  TyInfo ti = ty_from_block(blockIdx.x, e0, e1, e2, e3);
  const int* dstp = ti.ep + ti.E;
  for (int i = threadIdx.x; i < ti.nb; i += 256) h[i] = 0;
  __syncthreads();
  int jend = min(ti.E, (ti.cb + 1) * CHUNK);
  for (int j = ti.cb * CHUNK + threadIdx.x; j < jend; j += 256)
    atomicAdd(&h[dstp[j] >> 8], 1);
  __syncthreads();
  for (int i = threadIdx.x; i < ti.nb; i += 256) {
    int v = h[i];
    if (v) atomicAdd(&bh[ti.bhoff + i], v);
  }
}

__global__ __launch_bounds__(1024) void bucket_scan(const int* __restrict__ bh,
                                                    int* __restrict__ bb,
                                                    int* __restrict__ gcur) {
  __shared__ int s[1024];
  int ty = blockIdx.x;
  int nb = (ty == 0) ? NB0 : (ty == 1) ? NB1 : (ty == 2) ? NB2 : NB3;
  int E = (ty == 0) ? kEPT : (ty == 1) ? kETP : (ty == 2) ? kEAT : kETA;
  int bhoff = (ty == 0) ? 0 : (ty == 1) ? NB0 : (ty == 2) ? NB0 + NB1
                                               : NB0 + NB1 + NB2;
  int boff = bhoff + ty;
  int t = threadIdx.x;
  int v = (t < nb) ? bh[bhoff + t] : 0;
  s[t] = v;
  __syncthreads();
  for (int o = 1; o < 1024; o <<= 1) {
    int x = (t >= o) ? s[t - o] : 0;
    __syncthreads();
    s[t] += x;
    __syncthreads();
  }
  if (t < nb) {
    int ex = s[t] - v;
    bb[boff + t] = ex;
    gcur[bhoff + t] = ex;
  }
  if (t == 0) bb[boff + nb] = E;
}

__global__ __launch_bounds__(256) void bin_edges(
    const int* __restrict__ e0, const int* __restrict__ e1,
    const int* __restrict__ e2, const int* __restrict__ e3,
    int* __restrict__ gcur, int* __restrict__ bin) {
  __shared__ int h[NB0];
  __shared__ int hb[NB0];
  TyInfo ti = ty_from_block(blockIdx.x, e0, e1, e2, e3);
  const int* dstp = ti.ep + ti.E;
  for (int i = threadIdx.x; i < ti.nb; i += 256) h[i] = 0;
  __syncthreads();
  int j0 = ti.cb * CHUNK + threadIdx.x;
  int jend = min(ti.E, (ti.cb + 1) * CHUNK);
  for (int j = j0; j < jend; j += 256) atomicAdd(&h[dstp[j] >> 8], 1);
  __syncthreads();
  for (int i = threadIdx.x; i < ti.nb; i += 256) {
    int v = h[i];
    hb[i] = v ? atomicAdd(&gcur[ti.bhoff + i], v) : 0;
    h[i] = 0;
  }
  __syncthreads();
  for (int j = j0; j < jend; j += 256) {
    int d = dstp[j];
    int b = d >> 8;
    int pos = hb[b] + atomicAdd(&h[b], 1);
    bin[ti.eoff + pos] = ti.ep[j] | ((d & 255) << 24);
  }
}

__global__ __launch_bounds__(256) void fine_fill(
    const int* __restrict__ bin, const int* __restrict__ bb,
    int* __restrict__ rp0, int* __restrict__ rp1, int* __restrict__ rp2,
    int* __restrict__ rp3, int* __restrict__ co0, int* __restrict__ co1,
    int* __restrict__ co2, int* __restrict__ co3) {
  __shared__ int cnt[256];
  __shared__ int excl[256];
  int b = blockIdx.x;
  int ty, lb;
  if (b < NB0) { ty = 0; lb = b; }
  else if (b < NB0 + NB1) { ty = 1; lb = b - NB0; }
  else if (b < NB0 + NB1 + NB2) { ty = 2; lb = b - NB0 - NB1; }
  else { ty = 3; lb = b - NB0 - NB1 - NB2; }
  int nb = (ty == 0) ? NB0 : (ty == 1) ? NB1 : (ty == 2) ? NB2 : NB3;
  int N = (ty == 0) ? kNT : (ty == 1) ? kNP : (ty == 2) ? kNT : kNA;
  int E = (ty == 0) ? kEPT : (ty == 1) ? kETP : (ty == 2) ? kEAT : kETA;
  int bhoff = (ty == 0) ? 0 : (ty == 1) ? NB0 : (ty == 2) ? NB0 + NB1
                                               : NB0 + NB1 + NB2;
  int boff = bhoff + ty;
  int eoff = (ty == 0) ? 0 : (ty == 1) ? kEPT : (ty == 2) ? kEPT + kETP
                                                : kEPT + kETP + kEAT;
  int* rp = (ty == 0) ? rp0 : (ty == 1) ? rp1 : (ty == 2) ? rp2 : rp3;
  int* col = (ty == 0) ? co0 : (ty == 1) ? co1 : (ty == 2) ? co2 : co3;

  int base = bb[boff + lb];
  int end = bb[boff + lb + 1];
  int t = threadIdx.x;
  cnt[t] = 0;
  __syncthreads();
  for (int j = base + t; j < end; j += 256)
    atomicAdd(&cnt[(bin[eoff + j] >> 24) & 255], 1);
  __syncthreads();
  int v = cnt[t];
  excl[t] = v;
  __syncthreads();
  for (int o = 1; o < 256; o <<= 1) {
    int x = (t >= o) ? excl[t - o] : 0;
    __syncthreads();
    excl[t] += x;
    __syncthreads();
  }
  excl[t] -= v;
  cnt[t] = 0;
  __syncthreads();
  int node = (lb << 8) + t;
  if (node < N) rp[node] = base + excl[t];
  if (lb == nb - 1 && t == 0) rp[N] = E;
  for (int j = base + t; j < end; j += 256) {
    int v2 = bin[eoff + j];
    int l = (v2 >> 24) & 255;
    int pos = base + excl[l] + atomicAdd(&cnt[l], 1);
    col[pos] = v2 & 0xFFFFFF;
  }
}

// ---------------- gathers (4-edge batched loads, fp32 acc, bf16 out) ---------

__device__ __forceinline__ void gacc(const short8* __restrict__ Xv, int ldx8,
                                     int off8c, const int* __restrict__ col,
                                     int s, int e, float acc[8]) {
  int j = s;
  for (; j + 4 <= e; j += 4) {
    short8 v0 = Xv[(size_t)col[j] * ldx8 + off8c];
    short8 v1 = Xv[(size_t)col[j + 1] * ldx8 + off8c];
    short8 v2 = Xv[(size_t)col[j + 2] * ldx8 + off8c];
    short8 v3 = Xv[(size_t)col[j + 3] * ldx8 + off8c];
#pragma unroll
    for (int i = 0; i < 8; ++i)
      acc[i] += (bf2f(v0[i]) + bf2f(v1[i])) + (bf2f(v2[i]) + bf2f(v3[i]));
  }
  for (; j < e; ++j) {
    short8 v = Xv[(size_t)col[j] * ldx8 + off8c];
#pragma unroll
    for (int i = 0; i < 8; ++i) acc[i] += bf2f(v[i]);
  }
}

__global__ __launch_bounds__(256) void gather4(
    const short* __restrict__ xpeb, const short* __restrict__ xaeb,
    const short* __restrict__ xtb, const int* __restrict__ rp_pt,
    const int* __restrict__ col_pt, short* __restrict__ aggpt,
    const int* __restrict__ rp_at, const int* __restrict__ col_at,
    short* __restrict__ aggat, const int* __restrict__ rp_tp,
    const int* __restrict__ col_tp, short* __restrict__ aggtp,
    const int* __restrict__ rp_ta, const int* __restrict__ col_ta,
    short* __restrict__ aggta) {
  constexpr int R0 = kNT, R1 = 2 * kNT, R2 = 2 * kNT + kNP,
                R3 = 2 * kNT + kNP + kNA;
  int g = blockIdx.x * 16 + (int)threadIdx.x / 16;
  int c = (int)threadIdx.x % 16;
  const short* X;
  const int* rp;
  const int* col;
  short* out;
  int r;
  if (g < R0) { X = xpeb; rp = rp_pt; col = col_pt; out = aggpt; r = g; }
  else if (g < R1) { X = xaeb; rp = rp_at; col = col_at; out = aggat; r = g - R0; }
  else if (g < R2) { X = xtb; rp = rp_tp; col = col_tp; out = aggtp; r = g - R1; }
  else if (g < R3) { X = xtb; rp = rp_ta; col = col_ta; out = aggta; r = g - R2; }
  else return;
  int s = rp[r], e = rp[r + 1];
  float acc[8] = {0.f, 0.f, 0.f, 0.f, 0.f, 0.f, 0.f, 0.f};
  gacc(reinterpret_cast<const short8*>(X), 16, c, col, s, e, acc);
  float inv = 1.0f / fmaxf((float)(e - s), 1.0f);
  short8 w;
#pragma unroll
  for (int i = 0; i < 8; ++i) w[i] = f2bf(acc[i] * inv);
  reinterpret_cast<short8*>(out)[(size_t)r * 16 + c] = w;
}

__global__ __launch_bounds__(256) void gather_tpta(
    const short* __restrict__ ypab, const int* __restrict__ rp_tp,
    const int* __restrict__ col_tp, short* __restrict__ g_tp,
    const int* __restrict__ rp_ta, const int* __restrict__ col_ta,
    short* __restrict__ g_ta) {
  int g = blockIdx.x * 16 + (int)threadIdx.x / 16;
  int c = (int)threadIdx.x % 16;
  const int* rp;
  const int* col;
  short* out;
  int r, off8;
  if (g < kNP) { rp = rp_tp; col = col_tp; out = g_tp; r = g; off8 = 0; }
  else if (g < kNP + kNA) { rp = rp_ta; col = col_ta; out = g_ta; r = g - kNP; off8 = 16; }
  else return;
  int s = rp[r], e = rp[r + 1];
  float acc[8] = {0.f, 0.f, 0.f, 0.f, 0.f, 0.f, 0.f, 0.f};
  gacc(reinterpret_cast<const short8*>(ypab), 32, off8 + c, col, s, e, acc);
  float inv = 1.0f / fmaxf((float)(e - s), 1.0f);
  short8 w;
#pragma unroll
  for (int i = 0; i < 8; ++i) w[i] = f2bf(acc[i] * inv);
  reinterpret_cast<short8*>(out)[(size_t)r * 16 + c] = w;
}

__global__ __launch_bounds__(256) void gather2_b(
    const short* __restrict__ X1, const int* __restrict__ rp1,
    const int* __restrict__ col1, const short* __restrict__ X2,
    const int* __restrict__ rp2, const int* __restrict__ col2,
    short* __restrict__ out, int N) {
  int g = blockIdx.x * 16 + (int)threadIdx.x / 16;
  int c = (int)threadIdx.x % 16;
  if (g >= N) return;
  float tot[8] = {0.f, 0.f, 0.f, 0.f, 0.f, 0.f, 0.f, 0.f};
  {
    int s = rp1[g], e = rp1[g + 1];
    float a[8] = {0.f, 0.f, 0.f, 0.f, 0.f, 0.f, 0.f, 0.f};
    gacc(reinterpret_cast<const short8*>(X1), 16, c, col1, s, e, a);
    float inv = 1.0f / fmaxf((float)(e - s), 1.0f);
#pragma unroll
    for (int i = 0; i < 8; ++i) tot[i] += a[i] * inv;
  }
  {
    int s = rp2[g], e = rp2[g + 1];
    float a[8] = {0.f, 0.f, 0.f, 0.f, 0.f, 0.f, 0.f, 0.f};
    gacc(reinterpret_cast<const short8*>(X2), 16, c, col2, s, e, a);
    float inv = 1.0f / fmaxf((float)(e - s), 1.0f);
#pragma unroll
    for (int i = 0; i < 8; ++i) tot[i] += a[i] * inv;
  }
  short8 w;
#pragma unroll
  for (int i = 0; i < 8; ++i) w[i] = f2bf(tot[i]);
  reinterpret_cast<short8*>(out)[(size_t)g * 16 + c] = w;
}

// ------- MFMA GEMM (WC=8, no duplicated B loads) — p_out/a_out ---------------
// C fp32 = A@B + bias + bf2f(add0);  A [N][256], B frag D=128 K=256.

struct GemmP {
  const short* A0;
  const short* B0;
  const float* bias; const short* add0;
  float* Cf; int N;
};

__device__ __forceinline__ void gemm_core(const GemmP& p, int blk) {
  constexpr int K = 256;
  constexpr int KCH = K / 32;  // 8

  __shared__ short As[2][64 * 128];

  const int tid = threadIdx.x;
  const int lane = tid & 63;
  const int w = tid >> 6;
  const int lr = lane & 15;
  const int ls = lane >> 4;
  const int n0 = blk * 64;
  const int N = p.N;

  auto stage = [&](int buf, int kc) {
#pragma unroll
    for (int it = 0; it < 2; ++it) {
      int u = it * 512 + w * 64 + lane;
      int row = u >> 4;
      int c8s = u & 15;
      int n = n0 + row;
      if (n >= N) n = N - 1;
      const short* g = p.A0 + (size_t)n * K + kc + ((c8s ^ (row & 7)) << 3);
      short* l = &As[buf][(it * 512 + w * 64) * 8];
      __builtin_amdgcn_global_load_lds(
          (const __attribute__((address_space(1))) void*)g,
          (__attribute__((address_space(3))) void*)l, 16, 0, 0);
    }
  };

  f32x4 acc[4] = {};

  stage(0, 0);
  __syncthreads();

#pragma unroll
  for (int c = 0; c < 2; ++c) {
    const int buf = c & 1;
    const int kc32 = c * 4;
    short8 bfr[4];
#pragma unroll
    for (int kk = 0; kk < 4; ++kk)
      bfr[kk] = *reinterpret_cast<const short8*>(
          p.B0 + ((size_t)(w * KCH + kc32 + kk) * 64 + lane) * 8);
    __builtin_amdgcn_sched_barrier(0);
    if (c == 0) stage(1, 128);
    __builtin_amdgcn_sched_barrier(0);
#pragma unroll
    for (int kk = 0; kk < 4; ++kk) {
#pragma unroll
      for (int tm = 0; tm < 4; ++tm) {
        int row = tm * 16 + lr;
        short8 af = *reinterpret_cast<const short8*>(
            &As[buf][(row * 128 + (kk * 4 + ls) * 8) ^ ((row & 7) << 3)]);
        acc[tm] = __builtin_amdgcn_mfma_f32_16x16x32_bf16(af, bfr[kk], acc[tm],
                                                          0, 0, 0);
      }
    }
    __syncthreads();
  }

  int colg = w * 16 + lr;
  float bv = p.bias[colg];
#pragma unroll
  for (int tm = 0; tm < 4; ++tm) {
#pragma unroll
    for (int r = 0; r < 4; ++r) {
      int n = n0 + tm * 16 + ls * 4 + r;
      if (n < N) {
        float v = acc[tm][r] + bv + bf2f(p.add0[(size_t)n * 128 + colg]);
        p.Cf[(size_t)n * 128 + colg] = v;
      }
    }
  }
}

__global__ __launch_bounds__(512, 4) void mfma_gemm_pair(GemmP pa, GemmP pb,
                                                         int split) {
  if ((int)blockIdx.x < split)
    gemm_core(pa, blockIdx.x);
  else
    gemm_core(pb, blockIdx.x - split);
}

// ------- MEGA (WC=8): conv1 GEMM -> LDS tile -> fused K=256 GEMM -------------
// Phase A: H = relu(sum_a A_a @ Wa_a + abias) -> LDS [64][256] (+Astore if !TRACK)
// Phase B TRACK: D=384 GEMM vs wdual: cols 0-127 -> t_out(+gt+bc), 128-383 -> ypab
// Phase B pa:    D=128 GEMM vs Wb -> B1b (ypb/yab)

struct MegaP {
  const short* A0; const short* A1; const short* A2;
  const short* Wa0; const short* Wa1; const short* Wa2;  // frag D=256,K=128
  const float* abias;
  short* Astore;         // pa: p1b/a1b
  const short* Wb;       // TRACK: wdual (3xD=128,K=256); pa: w2l seg
  const float* bcmb;     // TRACK: bc
  const short* gt;       // TRACK
  float* tout;           // TRACK
  short* ypab;           // TRACK
  short* B1b;            // pa
  int N;
};

template <int NA, bool TRACK>
__device__ __forceinline__ void mega_core(const MegaP& p, int blk) {
  constexpr int TNB = TRACK ? 3 : 1;

  __shared__ short As[2][64 * 128];
  short* t1s = &As[0][0];  // [64][256] swizzled after phase A

  const int tid = threadIdx.x;
  const int lane = tid & 63;
  const int w = tid >> 6;  // 0..7
  const int lr = lane & 15;
  const int ls = lane >> 4;
  const int n0 = blk * 64;
  const int N = p.N;

  const short* Ap[3] = {p.A0, p.A1, p.A2};
  const short* Wp[3] = {p.Wa0, p.Wa1, p.Wa2};

  auto stage = [&](int buf, int a) {
#pragma unroll
    for (int it = 0; it < 2; ++it) {
      int u = it * 512 + w * 64 + lane;
      int row = u >> 4;
      int c8s = u & 15;
      int n = n0 + row;
      if (n >= N) n = N - 1;
      const short* g = Ap[a] + (size_t)n * 128 + ((c8s ^ (row & 7)) << 3);
      short* l = &As[buf][(it * 512 + w * 64) * 8];
      __builtin_amdgcn_global_load_lds(
          (const __attribute__((address_space(1))) void*)g,
          (__attribute__((address_space(3))) void*)l, 16, 0, 0);
    }
  };

  // ---- phase A (DOUT=256, WC=8, TN=2, TM=4) ----
  f32x4 acc[4][2] = {};
  stage(0, 0);
  __syncthreads();
#pragma unroll
  for (int c = 0; c < NA; ++c) {
    const int buf = c & 1;
    const short* Ba = Wp[c];
    short8 bfr[4][2];
#pragma unroll
    for (int kk = 0; kk < 4; ++kk)
#pragma unroll
      for (int tn = 0; tn < 2; ++tn)
        bfr[kk][tn] = *reinterpret_cast<const short8*>(
            Ba + ((size_t)((w * 2 + tn) * 4 + kk) * 64 + lane) * 8);
    __builtin_amdgcn_sched_barrier(0);
    if (c + 1 < NA) stage(buf ^ 1, c + 1);
    __builtin_amdgcn_sched_barrier(0);
#pragma unroll
    for (int kk = 0; kk < 4; ++kk) {
#pragma unroll
      for (int tm = 0; tm < 4; ++tm) {
        int row = tm * 16 + lr;
        short8 af = *reinterpret_cast<const short8*>(
            &As[buf][(row * 128 + (kk * 4 + ls) * 8) ^ ((row & 7) << 3)]);
#pragma unroll
        for (int tn = 0; tn < 2; ++tn)
          acc[tm][tn] = __builtin_amdgcn_mfma_f32_16x16x32_bf16(
              af, bfr[kk][tn], acc[tm][tn], 0, 0, 0);
      }
    }
    __syncthreads();
  }

  // ---- phase A epilogue: relu+bias -> bf16 LDS tile (+ optional global) ----
#pragma unroll
  for (int tm = 0; tm < 4; ++tm) {
#pragma unroll
    for (int tn = 0; tn < 2; ++tn) {
      int colg = w * 32 + tn * 16 + lr;
      float bv = p.abias[colg];
#pragma unroll
      for (int r = 0; r < 4; ++r) {
        int row = tm * 16 + ls * 4 + r;
        int n = n0 + row;
        float v = fmaxf(acc[tm][tn][r] + bv, 0.f);
        short b = f2bf(v);
        t1s[row * 256 + (colg ^ ((row & 7) << 3))] = b;
        if constexpr (!TRACK) {
          if (n < N) p.Astore[(size_t)n * 256 + colg] = b;
        }
      }
    }
  }
  __syncthreads();

  // ---- phase B: K=256 from LDS, DOUT = TNB*128 over 8 waves ----
  f32x4 bacc[4][TNB] = {};
#pragma unroll
  for (int kk = 0; kk < 8; ++kk) {
    short8 bfb[TNB];
#pragma unroll
    for (int tn = 0; tn < TNB; ++tn)
      bfb[tn] = *reinterpret_cast<const short8*>(
          p.Wb + ((size_t)((w * TNB + tn) * 8 + kk) * 64 + lane) * 8);
#pragma unroll
    for (int tm = 0; tm < 4; ++tm) {
      int row = tm * 16 + lr;
      short8 af = *reinterpret_cast<const short8*>(
          &t1s[(row * 256 + kk * 32 + ls * 8) ^ ((row & 7) << 3)]);
#pragma unroll
      for (int tn = 0; tn < TNB; ++tn)
        bacc[tm][tn] = __builtin_amdgcn_mfma_f32_16x16x32_bf16(
            af, bfb[tn], bacc[tm][tn], 0, 0, 0);
    }
  }
  // phase B epilogue
#pragma unroll
  for (int tm = 0; tm < 4; ++tm) {
#pragma unroll
    for (int tn = 0; tn < TNB; ++tn) {
      int colg = (w * TNB + tn) * 16 + lr;
#pragma unroll
      for (int r = 0; r < 4; ++r) {
        int n = n0 + tm * 16 + ls * 4 + r;
        if (n < N) {
          float v = bacc[tm][tn][r];
          if constexpr (TRACK) {
            if (colg < 128) {
              v += p.bcmb[colg] + bf2f(p.gt[(size_t)n * 128 + colg]);
              p.tout[(size_t)n * 128 + colg] = v;
            } else {
              p.ypab[(size_t)n * 256 + (colg - 128)] = f2bf(v);
            }
          } else {
            p.B1b[(size_t)n * 128 + colg] = f2bf(v);
          }
        }
      }
    }
  }
}

template <int NA, bool TRACK>
__global__ __launch_bounds__(512, 4) void mega_kernel(MegaP p) {
  mega_core<NA, TRACK>(p, blockIdx.x);
}

template <int NA, bool TRACK>
__global__ __launch_bounds__(512, 4) void mega_pair(MegaP pa, MegaP pb,
                                                    int split) {
  if ((int)blockIdx.x < split)
    mega_core<NA, TRACK>(pa, blockIdx.x);
  else
    mega_core<NA, TRACK>(pb, blockIdx.x - split);
}

}  // namespace

extern "C" void kernel_launch(void* const* d_in, const int* in_sizes, int n_in,
                              void* d_out, int out_size, void* d_ws,
                              size_t ws_size, hipStream_t stream) {
  const float* x_p   = (const float*)d_in[0];
  const float* x_t   = (const float*)d_in[1];
  const float* x_a   = (const float*)d_in[2];
  const float* emb_p = (const float*)d_in[3];
  const float* emb_a = (const float*)d_in[4];
  const float* W1l   = (const float*)d_in[5];
  const float* b1    = (const float*)d_in[6];
  const float* W1r   = (const float*)d_in[7];
  const float* W2l   = (const float*)d_in[8];
  const float* b2    = (const float*)d_in[9];
  const float* W2r   = (const float*)d_in[10];
  const float* Wres  = (const float*)d_in[11];
  const float* bres  = (const float*)d_in[12];
  const int* e_pt = (const int*)d_in[13];
  const int* e_tp = (const int*)d_in[14];
  const int* e_at = (const int*)d_in[15];
  const int* e_ta = (const int*)d_in[16];
  (void)in_sizes; (void)n_in; (void)out_size; (void)ws_size;

  float* out = (float*)d_out;
  float* p_out = out;
  float* t_out = out + (size_t)kNP * DO;
  float* a_out = out + (size_t)(kNP + kNT) * DO;

  char* base = (char*)d_ws;
  size_t off = 0;
  auto alloc = [&](size_t bytes) {
    off = (off + 255) & ~size_t(255);
    void* p = base + off;
    off += bytes;
    return p;
  };

  short* ypab  = (short*)alloc((size_t)kNT * DH * 2);
  short* gt    = (short*)alloc((size_t)kNT * DO * 2);
  short* p1b   = (short*)alloc((size_t)kNP * DH * 2);
  short* a1b   = (short*)alloc((size_t)kNA * DH * 2);
  short* aggpt = (short*)alloc((size_t)kNT * DIN * 2);
  short* aggat = (short*)alloc((size_t)kNT * DIN * 2);
  short* aggtp = (short*)alloc((size_t)kNP * DIN * 2);
  short* aggta = (short*)alloc((size_t)kNA * DIN * 2);
  short* xpeb  = (short*)alloc((size_t)kNP * DIN * 2);
  short* xaeb  = (short*)alloc((size_t)kNA * DIN * 2);
  short* xtb   = (short*)alloc((size_t)kNT * DIN * 2);
  short* ypb   = (short*)alloc((size_t)kNP * DO * 2);
  short* yab   = (short*)alloc((size_t)kNA * DO * 2);
  short* g_tp  = (short*)alloc((size_t)kNP * DO * 2);
  short* g_ta  = (short*)alloc((size_t)kNA * DO * 2);
  short* w1l_rm  = (short*)alloc(4 * per1 * 2);
  short* w1r_rm  = (short*)alloc(4 * per1 * 2);
  short* w1rc_rm = (short*)alloc(per1 * 2);
  short* w2l_rm  = (short*)alloc(4 * per2 * 2);
  short* wc_rm   = (short*)alloc(3 * per2 * 2);
  short* w1lb   = (short*)alloc(4 * per1 * 2);
  short* w1rb   = (short*)alloc(4 * per1 * 2);
  short* w1rcb  = (short*)alloc(per1 * 2);
  short* w2lb   = (short*)alloc(4 * per2 * 2);
  short* wcb    = (short*)alloc(3 * per2 * 2);
  short* wdual  = (short*)alloc(3 * per2 * 2);
  float* bc     = (float*)alloc(3 * DO * 4);
  float* b1ct   = (float*)alloc(DH * 4);

  int* rp_pt  = (int*)alloc((kNT + 1) * 4);
  int* rp_tp  = (int*)alloc((kNP + 1) * 4);
  int* rp_at  = (int*)alloc((kNT + 1) * 4);
  int* rp_ta  = (int*)alloc((kNA + 1) * 4);
  int* col_pt = (int*)alloc(kEPT * 4);
  int* col_tp = (int*)alloc(kETP * 4);
  int* col_at = (int*)alloc(kEAT * 4);
  int* col_ta = (int*)alloc(kETA * 4);
  int* bh     = (int*)alloc(NBTOT * 4);
  int* bb     = (int*)alloc(BBTOT * 4);
  int* gcur   = (int*)alloc(NBTOT * 4);
  int* bin    = (int*)alloc((size_t)(kEPT + kETP + kEAT + kETA) * 4);

  // ---- 0. fused converts ----
  {
    int tot = kNP * DIN / 8 + kNA * DIN / 8 + kNT * DIN / 8;
    cvt_all<<<cdiv(tot, 256), 256, 0, stream>>>(x_p, emb_p, xpeb, x_a, emb_a,
                                                xaeb, x_t, xtb);
  }

  // ---- 1. fused weight prep + fragment swizzle ----
  {
    int tot = 4 * per1 + 4 * per1 + per1 + 4 * per2 + 3 * per2 + DH;
    prep_all<<<cdiv(tot, 256), 256, 0, stream>>>(
        W1l, W1r, W2l, Wres, W2r, bres, b2, b1, w1l_rm, w1r_rm, w1rc_rm,
        w2l_rm, wc_rm, bc, b1ct);
    swizzle_all<<<cdiv(77824, 256), 256, 0, stream>>>(
        w1l_rm, w1lb, w1r_rm, w1rb, w1rc_rm, w1rcb, w2l_rm, w2lb, wc_rm, wcb,
        wdual);
  }

  // ---- 2. CSR build (bucketed counting sort) ----
  hipMemsetAsync(bh, 0, NBTOT * 4, stream);
  bucket_hist<<<CBTOT, 256, 0, stream>>>(e_pt, e_tp, e_at, e_ta, bh);
  bucket_scan<<<4, 1024, 0, stream>>>(bh, bb, gcur);
  bin_edges<<<CBTOT, 256, 0, stream>>>(e_pt, e_tp, e_at, e_ta, gcur, bin);
  fine_fill<<<NBTOT, 256, 0, stream>>>(bin, bb, rp_pt, rp_tp, rp_at, rp_ta,
                                       col_pt, col_tp, col_at, col_ta);

  // ---- 3. conv1 gathers (one launch) ----
  gather4<<<cdiv(2 * kNT + kNP + kNA, 16), 256, 0, stream>>>(
      xpeb, xaeb, xtb, rp_pt, col_pt, aggpt, rp_at, col_at, aggat, rp_tp,
      col_tp, aggtp, rp_ta, col_ta, aggta);

  // ---- 4. mega_pa: conv1 p/a GEMM + fused down-projection ----
  {
    MegaP mp = {aggtp, xpeb, nullptr, w1lb + 1 * per1, w1rb + 1 * per1,
                nullptr, b1 + 1 * DH, p1b, w2lb + 0 * per2, nullptr, nullptr,
                nullptr, nullptr, ypb, kNP};
    MegaP ma = {aggta, xaeb, nullptr, w1lb + 3 * per1, w1rb + 3 * per1,
                nullptr, b1 + 3 * DH, a1b, w2lb + 2 * per2, nullptr, nullptr,
                nullptr, nullptr, yab, kNA};
    int split = cdiv(kNP, 64);
    mega_pair<2, false>
        <<<split + cdiv(kNA, 64), 512, 0, stream>>>(mp, ma, split);
  }

  // ---- 5. gt = mean_pt(y_p) + mean_at(y_a) ----
  gather2_b<<<cdiv(kNT, 16), 256, 0, stream>>>(ypb, rp_pt, col_pt, yab, rp_at,
                                               col_at, gt, kNT);

  // ---- 6. mega_t: conv1-t GEMM + fused D=384 {t_out, ypab} ----
  {
    MegaP mt = {aggpt, aggat, xtb, w1lb + 0 * per1, w1lb + 2 * per1, w1rcb,
                b1ct, nullptr, wdual, bc + 0 * DO, gt, t_out, ypab, nullptr,
                kNT};
    mega_kernel<3, true><<<cdiv(kNT, 64), 512, 0, stream>>>(mt);
  }

  // ---- 7. conv2 tp/ta gathers ----
  gather_tpta<<<cdiv(kNP + kNA, 16), 256, 0, stream>>>(
      ypab, rp_tp, col_tp, g_tp, rp_ta, col_ta, g_ta);

  // ---- 8. p_out / a_out (paired, WC=8) ----
  {
    GemmP pp = {p1b, wcb + per2, bc + DO, g_tp, p_out, kNP};
    GemmP pa = {a1b, wcb + 2 * per2, bc + 2 * DO, g_ta, a_out, kNA};
    int split = cdiv(kNP, 64);
    mfma_gemm_pair<<<split + cdiv(kNA, 64), 512, 0, stream>>>(pp, pa, split);
  }
}